// Round 2
// baseline (569.942 us; speedup 1.0000x reference)
//
#include <hip/hip_runtime.h>
#include <hip/hip_bf16.h>

typedef unsigned short u16;
typedef float f32x4 __attribute__((ext_vector_type(4)));
typedef short bf16x8 __attribute__((ext_vector_type(8)));
typedef short bf16x4 __attribute__((ext_vector_type(4)));

#define NTOK 392      // tokens per window (8*7*7)
#define CDIM 256
#define TOKS 50176    // total tokens (= 128 windows * 392)
#define BKP  400      // padded key stride in bias table
#define VTP  400      // padded Vt LDS row (k dim)
#define KPAD 40       // padded K LDS row (d dim 32 -> 40)

__device__ __forceinline__ u16 f2b(float x) {
  union { __hip_bfloat16 b; u16 u; } cv; cv.b = __float2bfloat16(x); return cv.u;
}

__device__ __forceinline__ f32x4 mfma16(bf16x4 a, bf16x4 b, f32x4 c) {
#if __has_builtin(__builtin_amdgcn_mfma_f32_16x16x16bf16_1k)
  return __builtin_amdgcn_mfma_f32_16x16x16bf16_1k(a, b, c, 0, 0, 0);
#else
  // tied-accumulator form: D==C is architecturally valid; compiler will not
  // alias a/b with the in-out operand.
  asm volatile("v_mfma_f32_16x16x16_bf16 %0, %1, %2, %0"
               : "+v"(c) : "v"(a), "v"(b));
  return c;
#endif
}

// ---------------- fp32 -> bf16 weight convert ----------------
__global__ void conv_kernel(const float* __restrict__ in, u16* __restrict__ out, int n) {
  int i = blockIdx.x * 256 + threadIdx.x;
  if (i < n) out[i] = f2b(in[i]);
}

// ---------------- LayerNorm (optionally fused roll+window-partition) ----------------
// permute=1: out token t is in window layout; source gathered through roll(-4,-3,-3).
__global__ __launch_bounds__(64) void ln_kernel(const float* __restrict__ x,
    const float* __restrict__ g, const float* __restrict__ b,
    u16* __restrict__ out, int permute) {
  const int t = blockIdx.x, lane = threadIdx.x;
  size_t src;
  if (permute) {
    int w = t / NTOK, n = t % NTOK;
    int wd = w >> 6, wh = (w >> 3) & 7, ww = w & 7;
    int td = n / 49, rr = n % 49, th = rr / 7, tw = rr % 7;
    int d  = (wd * 8 + td + 4) & 15;
    int hh = (wh * 7 + th + 3) % 56;
    int wc = (ww * 7 + tw + 3) % 56;
    src = ((size_t)((d * 56 + hh) * 56 + wc)) * CDIM;
  } else {
    src = (size_t)t * CDIM;
  }
  f32x4 v = *(const f32x4*)(x + src + lane * 4);
  float s  = v[0] + v[1] + v[2] + v[3];
  float s2 = v[0]*v[0] + v[1]*v[1] + v[2]*v[2] + v[3]*v[3];
  #pragma unroll
  for (int o = 1; o < 64; o <<= 1) { s += __shfl_xor(s, o); s2 += __shfl_xor(s2, o); }
  float mean = s * (1.f / CDIM);
  float var  = s2 * (1.f / CDIM) - mean * mean;
  float rs   = rsqrtf(var + 1e-5f);
  f32x4 gg = *(const f32x4*)(g + lane * 4);
  f32x4 bb = *(const f32x4*)(b + lane * 4);
  bf16x4 o4;
  #pragma unroll
  for (int j = 0; j < 4; ++j) o4[j] = (short)f2b((v[j] - mean) * rs * gg[j] + bb[j]);
  *(bf16x4*)(out + (size_t)t * CDIM + lane * 4) = o4;
}

// ---------------- relative position bias table: bias[h][n][BKP] ----------------
__global__ void bias_kernel(const float* __restrict__ rel, float* __restrict__ bias) {
  int idx = blockIdx.x * 256 + threadIdx.x;
  if (idx >= NTOK * NTOK) return;
  int n = idx / NTOK, m = idx % NTOK;
  int td = n / 49, th = (n % 49) / 7, tw = n % 7;
  int md = m / 49, mh = (m % 49) / 7, mw = m % 7;
  int ridx = (td - md + 7) * 169 + (th - mh + 6) * 13 + (tw - mw + 6);
  const float* rp = rel + (size_t)ridx * 8;
  #pragma unroll
  for (int h = 0; h < 8; ++h)
    bias[((size_t)h * NTOK + n) * BKP + m] = rp[h];
}

// ---------------- generic bf16 GEMM: C[M][N] = A[M][K] * B[N][K]^T ----------------
// 128x128 tile, BK=64, 4 waves (2x2 of 64x64), 16x16x32 MFMA, padded LDS (+8).
template<class Epi>
__global__ __launch_bounds__(256, 2) void gemm_bt(const u16* __restrict__ A,
    const u16* __restrict__ B, int K, Epi epi) {
  __shared__ __align__(16) u16 As[128 * 72];
  __shared__ __align__(16) u16 Bs[128 * 72];
  const int tid = threadIdx.x, lane = tid & 63, wv = tid >> 6;
  const int bm = blockIdx.y * 128, bn = blockIdx.x * 128;
  const int wm = (wv >> 1) * 64, wn = (wv & 1) * 64;
  const int l16 = lane & 15, g = lane >> 4;
  f32x4 acc[4][4];
  #pragma unroll
  for (int i = 0; i < 4; ++i)
    #pragma unroll
    for (int j = 0; j < 4; ++j) acc[i][j] = (f32x4){0.f, 0.f, 0.f, 0.f};
  for (int k0 = 0; k0 < K; k0 += 64) {
    #pragma unroll
    for (int c = tid; c < 1024; c += 256) {   // 128 rows x 8 chunks of 16B
      int row = c >> 3, cb = c & 7;
      *(bf16x8*)(As + row * 72 + cb * 8) = *(const bf16x8*)(A + (size_t)(bm + row) * K + k0 + cb * 8);
      *(bf16x8*)(Bs + row * 72 + cb * 8) = *(const bf16x8*)(B + (size_t)(bn + row) * K + k0 + cb * 8);
    }
    __syncthreads();
    #pragma unroll
    for (int kk = 0; kk < 2; ++kk) {
      bf16x8 fa[4], fb[4];
      #pragma unroll
      for (int i = 0; i < 4; ++i) fa[i] = *(const bf16x8*)(As + (wm + i * 16 + l16) * 72 + kk * 32 + g * 8);
      #pragma unroll
      for (int i = 0; i < 4; ++i) fb[i] = *(const bf16x8*)(Bs + (wn + i * 16 + l16) * 72 + kk * 32 + g * 8);
      #pragma unroll
      for (int mi = 0; mi < 4; ++mi)
        #pragma unroll
        for (int ni = 0; ni < 4; ++ni)
          acc[mi][ni] = __builtin_amdgcn_mfma_f32_16x16x32_bf16(fa[mi], fb[ni], acc[mi][ni], 0, 0, 0);
    }
    __syncthreads();
  }
  #pragma unroll
  for (int mi = 0; mi < 4; ++mi)
    #pragma unroll
    for (int ni = 0; ni < 4; ++ni)
      #pragma unroll
      for (int j = 0; j < 4; ++j)
        epi(bm + wm + mi * 16 + g * 4 + j, bn + wn + ni * 16 + l16, acc[mi][ni][j]);
}

// ---------------- epilogues ----------------
struct EpiQKV {  // scatter to q/k/v [w][h][n][32] bf16; +bias; q *= scale
  const float* __restrict__ qb;
  u16 *q, *k, *v;
  __device__ void operator()(int row, int col, float val) const {
    val += qb[col];
    int which = col >> 8, hd = col & 255;
    if (which == 0) val *= 0.17677669529663687f;     // 32^-0.5
    int w = row / NTOK, n = row % NTOK;
    size_t dst = (((size_t)w * 8 + (hd >> 5)) * NTOK + n) * 32 + (hd & 31);
    u16* p = which == 0 ? q : (which == 1 ? k : v);
    p[dst] = f2b(val);
  }
};

struct EpiProj {  // +bias, reverse-partition + unroll, + residual x -> xres (fp32)
  const float* __restrict__ pb;
  const float* __restrict__ x;
  float* xr;
  __device__ void operator()(int row, int col, float val) const {
    val += pb[col];
    int w = row / NTOK, n = row % NTOK;
    int wd = w >> 6, wh = (w >> 3) & 7, ww = w & 7;
    int td = n / 49, rr = n % 49, th = rr / 7, tw = rr % 7;
    int d  = (wd * 8 + td + 4) & 15;
    int hh = (wh * 7 + th + 3) % 56;
    int wc = (ww * 7 + tw + 3) % 56;
    size_t t = ((size_t)((d * 56 + hh) * 56 + wc)) * CDIM + col;
    xr[t] = x[t] + val;
  }
};

struct EpiFC1 {  // +bias, exact GELU, bf16 out (row stride 1024)
  const float* __restrict__ fb;
  u16* y;
  __device__ void operator()(int row, int col, float val) const {
    val += fb[col];
    val = 0.5f * val * (1.0f + erff(val * 0.70710678118654752f));
    y[(size_t)row * 1024 + col] = f2b(val);
  }
};

struct EpiFC2 {  // +bias, + residual xres, fp32 final out
  const float* __restrict__ fb;
  const float* __restrict__ xr;
  float* out;
  __device__ void operator()(int row, int col, float val) const {
    val += fb[col];
    size_t t = (size_t)row * CDIM + col;
    out[t] = xr[t] + val;
  }
};

// ---------------- flash-style window attention ----------------
// block = one (window, head). S^T = mfma(K, Q^T): P tile lands directly in the
// B-operand layout of the PV 16x16x16 mfma -> no cross-lane shuffles.
__global__ __launch_bounds__(256, 2) void attn_kernel(
    const u16* __restrict__ qb, const u16* __restrict__ kb,
    const u16* __restrict__ vb, const float* __restrict__ bias,
    u16* __restrict__ out) {
  __shared__ __align__(16) u16 Ks[NTOK * KPAD];
  __shared__ __align__(16) u16 Vt[32 * VTP];
  __shared__ unsigned char cnt[NTOK];
  const int w = blockIdx.x >> 3, h = blockIdx.x & 7;
  const int tid = threadIdx.x, lane = tid & 63, wv = tid >> 6;
  const size_t base = (size_t)(w * 8 + h) * (NTOK * 32);
  // zero the Vt pad columns (keys 392..399): they are multiplied by P=0 in the
  // PV MFMA -- if left as garbage a NaN pattern would give 0*NaN = NaN.
  if (tid < 256) Vt[(tid >> 3) * VTP + NTOK + (tid & 7)] = 0;
  // stage K rows (padded) and V transposed
  for (int c = tid; c < NTOK * 4; c += 256) {
    int r = c >> 2, cb = c & 3;
    *(bf16x8*)(Ks + r * KPAD + cb * 8) = *(const bf16x8*)(kb + base + r * 32 + cb * 8);
    union { bf16x8 v; u16 u[8]; } vvu;
    vvu.v = *(const bf16x8*)(vb + base + r * 32 + cb * 8);
    #pragma unroll
    for (int j = 0; j < 8; ++j) Vt[(cb * 8 + j) * VTP + r] = vvu.u[j];
  }
  // shift-mask region id per token (shifted coords -> original region)
  const int wd = w >> 6, wh = (w >> 3) & 7, ww = w & 7;
  for (int n = tid; n < NTOK; n += 256) {
    int td = n / 49, rr = n % 49, th = rr / 7, tw = rr % 7;
    int dd = wd * 8 + td, hh = wh * 7 + th, wc = ww * 7 + tw;
    int rd = dd < 8 ? 0 : (dd < 12 ? 1 : 2);
    int rh = hh < 49 ? 0 : (hh < 53 ? 1 : 2);
    int rw = wc < 49 ? 0 : (wc < 53 ? 1 : 2);
    cnt[n] = (unsigned char)(rd * 9 + rh * 3 + rw);
  }
  __syncthreads();
  const int l16 = lane & 15, g = lane >> 4;
  for (int qt = wv; qt * 16 < NTOK; qt += 4) {
    const int q0 = qt * 16;
    const int qq = q0 + l16;
    const int qc = qq < NTOK ? qq : NTOK - 1;
    const bf16x8 qf = *(const bf16x8*)(qb + base + (size_t)qc * 32 + g * 8);
    const int cq = cnt[qc];
    f32x4 o0 = {0.f,0.f,0.f,0.f}, o1 = {0.f,0.f,0.f,0.f};
    float mrun = -1e30f, lrun = 0.f;
    for (int k0 = 0; k0 < NTOK; k0 += 16) {
      int kr = k0 + l16; kr = kr < NTOK ? kr : NTOK - 1;
      bf16x8 kf = *(const bf16x8*)(Ks + kr * KPAD + g * 8);
      f32x4 zero = {0.f,0.f,0.f,0.f};
      f32x4 st = __builtin_amdgcn_mfma_f32_16x16x32_bf16(kf, qf, zero, 0, 0, 0);
      f32x4 bv = *(const f32x4*)(bias + ((size_t)h * NTOK + qc) * BKP + k0 + 4 * g);
      float sv[4];
      #pragma unroll
      for (int i = 0; i < 4; ++i) {
        int kk = k0 + 4 * g + i;
        int kcl = kk < NTOK ? kk : 0;
        float m = (cnt[kcl] == cq) ? 0.f : -100.f;
        sv[i] = kk < NTOK ? (st[i] + bv[i] + m) : -1e30f;
      }
      float tm = fmaxf(fmaxf(sv[0], sv[1]), fmaxf(sv[2], sv[3]));
      tm = fmaxf(tm, __shfl_xor(tm, 16));
      tm = fmaxf(tm, __shfl_xor(tm, 32));
      float mnew  = fmaxf(mrun, tm);
      float alpha = __expf(mrun - mnew);
      float p0 = __expf(sv[0] - mnew), p1 = __expf(sv[1] - mnew);
      float p2 = __expf(sv[2] - mnew), p3 = __expf(sv[3] - mnew);
      float ps = p0 + p1 + p2 + p3;
      ps += __shfl_xor(ps, 16); ps += __shfl_xor(ps, 32);
      lrun = lrun * alpha + ps;
      mrun = mnew;
      bf16x4 pf;
      pf[0] = (short)f2b(p0); pf[1] = (short)f2b(p1);
      pf[2] = (short)f2b(p2); pf[3] = (short)f2b(p3);
      #pragma unroll
      for (int j = 0; j < 4; ++j) { o0[j] *= alpha; o1[j] *= alpha; }
      bf16x4 v0 = *(const bf16x4*)(Vt + l16 * VTP + k0 + 4 * g);
      bf16x4 v1 = *(const bf16x4*)(Vt + (16 + l16) * VTP + k0 + 4 * g);
      o0 = mfma16(v0, pf, o0);
      o1 = mfma16(v1, pf, o1);
    }
    if (qq < NTOK) {
      float inv = 1.f / lrun;
      bf16x4 w0, w1;
      #pragma unroll
      for (int j = 0; j < 4; ++j) { w0[j] = (short)f2b(o0[j] * inv); w1[j] = (short)f2b(o1[j] * inv); }
      u16* op = out + ((size_t)(w * NTOK + qq)) * CDIM + h * 32;
      *(bf16x4*)(op + 4 * g) = w0;
      *(bf16x4*)(op + 16 + 4 * g) = w1;
    }
  }
}

// ---------------- launcher ----------------
extern "C" void kernel_launch(void* const* d_in, const int* in_sizes, int n_in,
                              void* d_out, int out_size, void* d_ws, size_t ws_size,
                              hipStream_t stream) {
  const float* x      = (const float*)d_in[0];
  const float* n1g    = (const float*)d_in[1];
  const float* n1b    = (const float*)d_in[2];
  const float* qkv_w  = (const float*)d_in[3];
  const float* qkv_b  = (const float*)d_in[4];
  const float* rel    = (const float*)d_in[5];
  const float* proj_w = (const float*)d_in[6];
  const float* proj_b = (const float*)d_in[7];
  const float* n2g    = (const float*)d_in[8];
  const float* n2b    = (const float*)d_in[9];
  const float* fc1_w  = (const float*)d_in[10];
  const float* fc1_b  = (const float*)d_in[11];
  const float* fc2_w  = (const float*)d_in[12];
  const float* fc2_b  = (const float*)d_in[13];
  float* out = (float*)d_out;
  char* ws = (char*)d_ws;

  const size_t SZB = (size_t)TOKS * CDIM * 2;          // 25,690,112 B (one bf16 plane)
  u16*   wins = (u16*)(ws);
  u16*   qbuf = (u16*)(ws + SZB);
  u16*   kbuf = (u16*)(ws + 2 * SZB);
  u16*   vbuf = (u16*)(ws + 3 * SZB);
  float* bias = (float*)(ws + 4 * SZB);                // 8*392*400*4 = 5,017,600 B
  u16*   aout = (u16*)(ws + 4 * SZB + 5017600);
  float* xres = (float*)(ws + 5 * SZB + 5017600);
  u16*   h2   = (u16*)(ws + 5 * SZB + 5017600 + (size_t)TOKS * CDIM * 4);
  u16*   wq   = (u16*)(ws + 6 * SZB + 5017600 + (size_t)TOKS * CDIM * 4);
  u16*   wp   = wq + 768 * 256;
  u16*   w1   = wp + 256 * 256;
  u16*   w2   = w1 + 1024 * 256;
  u16*   y1   = (u16*)(ws);                            // reuse wins..vbuf (dead by then)

  conv_kernel<<<768, 256, 0, stream>>>(qkv_w, wq, 196608);
  conv_kernel<<<256, 256, 0, stream>>>(proj_w, wp, 65536);
  conv_kernel<<<1024, 256, 0, stream>>>(fc1_w, w1, 262144);
  conv_kernel<<<1024, 256, 0, stream>>>(fc2_w, w2, 262144);
  ln_kernel<<<TOKS, 64, 0, stream>>>(x, n1g, n1b, wins, 1);
  bias_kernel<<<(NTOK * NTOK + 255) / 256, 256, 0, stream>>>(rel, bias);
  gemm_bt<<<dim3(6, 392), 256, 0, stream>>>(wins, wq, 256, EpiQKV{qkv_b, qbuf, kbuf, vbuf});
  attn_kernel<<<1024, 256, 0, stream>>>(qbuf, kbuf, vbuf, bias, aout);
  gemm_bt<<<dim3(2, 392), 256, 0, stream>>>(aout, wp, 256, EpiProj{proj_b, x, xres});
  ln_kernel<<<TOKS, 64, 0, stream>>>(xres, n2g, n2b, h2, 0);
  gemm_bt<<<dim3(8, 392), 256, 0, stream>>>(h2, w1, 256, EpiFC1{fc1_b, y1});
  gemm_bt<<<dim3(2, 392), 256, 0, stream>>>(y1, w2, 1024, EpiFC2{fc2_b, xres, out});
}